// Round 1
// baseline (2109.276 us; speedup 1.0000x reference)
//
#include <hip/hip_runtime.h>
#include <math.h>

#define D_MODEL   1024
#define NUM_HEADS 16
#define HEAD_DIM  64
#define B_SZ      4
#define L_SEQ     1024
#define BHC       (B_SZ * NUM_HEADS)   // 64

// ---------------- lambda scalars ----------------
__global__ void lam_kernel(const float* __restrict__ lq, const float* __restrict__ lk,
                           const float* __restrict__ lv, float* __restrict__ lam) {
    int t = threadIdx.x; // 64 threads
    float pc = lk[t] * lv[t];   // lam_cross = exp(sum(lambda_k * lambda_v)) -> multiplies QK term
    float ps = lq[t] * lk[t];   // lam_self  = exp(sum(lambda_q * lambda_k)) -> multiplies KV term
#pragma unroll
    for (int o = 32; o > 0; o >>= 1) {
        pc += __shfl_down(pc, o, 64);
        ps += __shfl_down(ps, o, 64);
    }
    if (t == 0) { lam[0] = expf(pc); lam[1] = expf(ps); }
}

// ---------------- GEMM: Y = X @ W^T + bias  (X[M,K], W[N,K]) ----------------
// headSplit=1: Y is [B,H,L,hd] head-split layout; else Y is [M,N] row-major.
__global__ __launch_bounds__(256) void gemm_bt_kernel(
    const float* __restrict__ X, const float* __restrict__ W,
    const float* __restrict__ bias, float* __restrict__ Y, int headSplit)
{
    constexpr int BM = 128, BN = 128, BK = 16;
    constexpr int K = D_MODEL, N = D_MODEL;
    __shared__ float As[BK][BM + 4];   // transposed: As[k][m]
    __shared__ float Bs[BK][BN + 4];   // transposed: Bs[k][n]

    int tid = threadIdx.x;
    int tx = tid & 15, ty = tid >> 4;
    int m0 = blockIdx.y * BM, n0 = blockIdx.x * BN;

    float acc[8][8] = {};

    for (int k0 = 0; k0 < K; k0 += BK) {
#pragma unroll
        for (int s = tid; s < 512; s += 256) {  // 512 float4 slots per operand tile
            int row = s >> 2, kc = (s & 3) * 4;
            float4 a = *(const float4*)&X[(size_t)(m0 + row) * K + k0 + kc];
            As[kc + 0][row] = a.x; As[kc + 1][row] = a.y;
            As[kc + 2][row] = a.z; As[kc + 3][row] = a.w;
            float4 b = *(const float4*)&W[(size_t)(n0 + row) * K + k0 + kc];
            Bs[kc + 0][row] = b.x; Bs[kc + 1][row] = b.y;
            Bs[kc + 2][row] = b.z; Bs[kc + 3][row] = b.w;
        }
        __syncthreads();
#pragma unroll
        for (int kk = 0; kk < BK; ++kk) {
            float4 a0 = *(const float4*)&As[kk][ty * 8];
            float4 a1 = *(const float4*)&As[kk][ty * 8 + 4];
            float4 b0 = *(const float4*)&Bs[kk][tx * 8];
            float4 b1 = *(const float4*)&Bs[kk][tx * 8 + 4];
            float av[8]  = {a0.x, a0.y, a0.z, a0.w, a1.x, a1.y, a1.z, a1.w};
            float bvv[8] = {b0.x, b0.y, b0.z, b0.w, b1.x, b1.y, b1.z, b1.w};
#pragma unroll
            for (int i = 0; i < 8; ++i)
#pragma unroll
                for (int j = 0; j < 8; ++j)
                    acc[i][j] = fmaf(av[i], bvv[j], acc[i][j]);
        }
        __syncthreads();
    }

#pragma unroll
    for (int i = 0; i < 8; ++i) {
        int m = m0 + ty * 8 + i;
        int bb = m >> 10, l = m & 1023;
#pragma unroll
        for (int j = 0; j < 8; ++j) {
            int n = n0 + tx * 8 + j;
            float v = acc[i][j] + bias[n];
            if (headSplit) {
                int h = n >> 6, d = n & 63;
                Y[(((size_t)(bb * NUM_HEADS + h)) * L_SEQ + l) * HEAD_DIM + d] = v;
            } else {
                Y[(size_t)m * N + n] = v;
            }
        }
    }
}

// ---------------- fused scores -> softmax (weights out) -> PV ----------------
// Per block: one (b,h) pair, 64 query rows. Combined K=128 contraction:
//   A[l] = [scale*lamC*Qh[l] | scale*lamS*Kh[l]],  B[m] = [Kh[m] | Vh[m]]
__global__ __launch_bounds__(256) void fused_attn_kernel(
    const float* __restrict__ Qh, const float* __restrict__ Kh, const float* __restrict__ Vh,
    const float* __restrict__ lam, float* __restrict__ attnW, float* __restrict__ AO)
{
    __shared__ float As[128][68];   // As[k][r]
    __shared__ float Bs[128][68];   // Bs[k][c]
    __shared__ float Vs[64][68];    // Vs[c][d] (V non-transposed, for PV)
    __shared__ float Ws[64][65];    // score/weight tile
    __shared__ float mrow[64], lrow[64];

    int tid = threadIdx.x;
    int tx = tid & 15, ty = tid >> 4;
    int rb = blockIdx.x;            // 0..15 row block
    int bh = blockIdx.y;            // 0..63
    int b = bh >> 4, h = bh & 15;
    size_t base = (size_t)bh * L_SEQ * HEAD_DIM;

    const float scale = 0.125f;     // 1/sqrt(64)
    float sA_q = scale * lam[0];    // lam_cross on QK term
    float sA_k = scale * lam[1];    // lam_self  on KV term

    // stage combined A (transposed), scaled
    for (int s = tid; s < 2048; s += 256) {
        int r = s >> 5;
        int k = (s & 31) * 4;
        int row = rb * 64 + r;
        float4 v; float sc;
        if (k < 64) { v = *(const float4*)&Qh[base + (size_t)row * 64 + k];        sc = sA_q; }
        else        { v = *(const float4*)&Kh[base + (size_t)row * 64 + (k - 64)]; sc = sA_k; }
        As[k + 0][r] = v.x * sc; As[k + 1][r] = v.y * sc;
        As[k + 2][r] = v.z * sc; As[k + 3][r] = v.w * sc;
    }
    if (tid < 64) { mrow[tid] = -INFINITY; lrow[tid] = 0.0f; }

    // ---------- pass 1: online row max / sum ----------
    for (int t = 0; t < 16; ++t) {
        __syncthreads();
        for (int s = tid; s < 2048; s += 256) {
            int c = s >> 5;
            int k = (s & 31) * 4;
            int col = t * 64 + c;
            float4 v;
            if (k < 64) v = *(const float4*)&Kh[base + (size_t)col * 64 + k];
            else {
                v = *(const float4*)&Vh[base + (size_t)col * 64 + (k - 64)];
                *(float4*)&Vs[c][k - 64] = v;
            }
            Bs[k + 0][c] = v.x; Bs[k + 1][c] = v.y; Bs[k + 2][c] = v.z; Bs[k + 3][c] = v.w;
        }
        __syncthreads();

        float acc[4][4] = {};
#pragma unroll 8
        for (int k = 0; k < 128; ++k) {
            float4 a  = *(const float4*)&As[k][ty * 4];
            float4 bv = *(const float4*)&Bs[k][tx * 4];
            float aa[4]  = {a.x, a.y, a.z, a.w};
            float bb4[4] = {bv.x, bv.y, bv.z, bv.w};
#pragma unroll
            for (int i = 0; i < 4; ++i)
#pragma unroll
                for (int j = 0; j < 4; ++j)
                    acc[i][j] = fmaf(aa[i], bb4[j], acc[i][j]);
        }
#pragma unroll
        for (int i = 0; i < 4; ++i)
#pragma unroll
            for (int j = 0; j < 4; ++j)
                Ws[ty * 4 + i][tx * 4 + j] = acc[i][j];
        __syncthreads();

        if (tid < 64) {
            int r = tid;
            float m_old = mrow[r];
            float tmax = -INFINITY;
            for (int c = 0; c < 64; ++c) tmax = fmaxf(tmax, Ws[r][c]);
            float m_new = fmaxf(m_old, tmax);
            float sum = 0.0f;
            for (int c = 0; c < 64; ++c) sum += expf(Ws[r][c] - m_new);
            lrow[r] = lrow[r] * expf(m_old - m_new) + sum;
            mrow[r] = m_new;
        }
    }
    __syncthreads();
    if (tid < 64) lrow[tid] = 1.0f / lrow[tid];

    // ---------- pass 2: weights write + PV ----------
    float Oacc[4][4] = {};
    for (int t = 0; t < 16; ++t) {
        __syncthreads();
        for (int s = tid; s < 2048; s += 256) {
            int c = s >> 5;
            int k = (s & 31) * 4;
            int col = t * 64 + c;
            float4 v;
            if (k < 64) v = *(const float4*)&Kh[base + (size_t)col * 64 + k];
            else {
                v = *(const float4*)&Vh[base + (size_t)col * 64 + (k - 64)];
                *(float4*)&Vs[c][k - 64] = v;
            }
            Bs[k + 0][c] = v.x; Bs[k + 1][c] = v.y; Bs[k + 2][c] = v.z; Bs[k + 3][c] = v.w;
        }
        __syncthreads();

        float acc[4][4] = {};
#pragma unroll 8
        for (int k = 0; k < 128; ++k) {
            float4 a  = *(const float4*)&As[k][ty * 4];
            float4 bv = *(const float4*)&Bs[k][tx * 4];
            float aa[4]  = {a.x, a.y, a.z, a.w};
            float bb4[4] = {bv.x, bv.y, bv.z, bv.w};
#pragma unroll
            for (int i = 0; i < 4; ++i)
#pragma unroll
                for (int j = 0; j < 4; ++j)
                    acc[i][j] = fmaf(aa[i], bb4[j], acc[i][j]);
        }

#pragma unroll
        for (int i = 0; i < 4; ++i) {
            int r = ty * 4 + i;
            float mr = mrow[r], ir = lrow[r];
            float w0 = expf(acc[i][0] - mr) * ir;
            float w1 = expf(acc[i][1] - mr) * ir;
            float w2 = expf(acc[i][2] - mr) * ir;
            float w3 = expf(acc[i][3] - mr) * ir;
            int row = rb * 64 + r;
            size_t idx = ((size_t)bh * L_SEQ + row) * L_SEQ + t * 64 + tx * 4;
            *(float4*)&attnW[idx] = make_float4(w0, w1, w2, w3);
            Ws[r][tx * 4 + 0] = w0; Ws[r][tx * 4 + 1] = w1;
            Ws[r][tx * 4 + 2] = w2; Ws[r][tx * 4 + 3] = w3;
        }
        __syncthreads();

#pragma unroll 4
        for (int c = 0; c < 64; ++c) {
            float a0 = Ws[ty * 4 + 0][c];
            float a1 = Ws[ty * 4 + 1][c];
            float a2 = Ws[ty * 4 + 2][c];
            float a3 = Ws[ty * 4 + 3][c];
            float4 bv = *(const float4*)&Vs[c][tx * 4];
            Oacc[0][0] = fmaf(a0, bv.x, Oacc[0][0]); Oacc[0][1] = fmaf(a0, bv.y, Oacc[0][1]);
            Oacc[0][2] = fmaf(a0, bv.z, Oacc[0][2]); Oacc[0][3] = fmaf(a0, bv.w, Oacc[0][3]);
            Oacc[1][0] = fmaf(a1, bv.x, Oacc[1][0]); Oacc[1][1] = fmaf(a1, bv.y, Oacc[1][1]);
            Oacc[1][2] = fmaf(a1, bv.z, Oacc[1][2]); Oacc[1][3] = fmaf(a1, bv.w, Oacc[1][3]);
            Oacc[2][0] = fmaf(a2, bv.x, Oacc[2][0]); Oacc[2][1] = fmaf(a2, bv.y, Oacc[2][1]);
            Oacc[2][2] = fmaf(a2, bv.z, Oacc[2][2]); Oacc[2][3] = fmaf(a2, bv.w, Oacc[2][3]);
            Oacc[3][0] = fmaf(a3, bv.x, Oacc[3][0]); Oacc[3][1] = fmaf(a3, bv.y, Oacc[3][1]);
            Oacc[3][2] = fmaf(a3, bv.z, Oacc[3][2]); Oacc[3][3] = fmaf(a3, bv.w, Oacc[3][3]);
        }
    }

    // write attn_out in [B, L, D] layout (merged heads)
#pragma unroll
    for (int i = 0; i < 4; ++i) {
        int l = rb * 64 + ty * 4 + i;
        size_t idx = ((size_t)b * L_SEQ + l) * D_MODEL + h * HEAD_DIM + tx * 4;
        *(float4*)&AO[idx] = make_float4(Oacc[i][0], Oacc[i][1], Oacc[i][2], Oacc[i][3]);
    }
}

extern "C" void kernel_launch(void* const* d_in, const int* in_sizes, int n_in,
                              void* d_out, int out_size, void* d_ws, size_t ws_size,
                              hipStream_t stream) {
    const float* q  = (const float*)d_in[0];
    const float* k  = (const float*)d_in[1];
    const float* v  = (const float*)d_in[2];
    const float* Wq = (const float*)d_in[3];
    const float* bq = (const float*)d_in[4];
    const float* Wk = (const float*)d_in[5];
    const float* bk = (const float*)d_in[6];
    const float* Wv = (const float*)d_in[7];
    const float* bv = (const float*)d_in[8];
    const float* Wo = (const float*)d_in[9];
    const float* bo = (const float*)d_in[10];
    const float* lq = (const float*)d_in[11];
    const float* lk = (const float*)d_in[12];
    const float* lv = (const float*)d_in[13];

    float* out   = (float*)d_out;                       // [4,1024,1024]
    float* attnW = out + (size_t)B_SZ * L_SEQ * D_MODEL; // [4,16,1024,1024]

    float* ws  = (float*)d_ws;
    float* Qh  = ws;                                   // [64,1024,64]
    float* Kh  = ws + (size_t)4194304;
    float* Vh  = ws + (size_t)8388608;
    float* AO  = ws + (size_t)12582912;                // [4,1024,1024]
    float* lam = ws + (size_t)16777216;                // 2 floats

    lam_kernel<<<1, 64, 0, stream>>>(lq, lk, lv, lam);

    dim3 ggrid(8, 32, 1);
    gemm_bt_kernel<<<ggrid, 256, 0, stream>>>(q, Wq, bq, Qh, 1);
    gemm_bt_kernel<<<ggrid, 256, 0, stream>>>(k, Wk, bk, Kh, 1);
    gemm_bt_kernel<<<ggrid, 256, 0, stream>>>(v, Wv, bv, Vh, 1);

    fused_attn_kernel<<<dim3(16, 64), 256, 0, stream>>>(Qh, Kh, Vh, lam, attnW, AO);

    gemm_bt_kernel<<<ggrid, 256, 0, stream>>>(AO, Wo, bo, out, 0);
}

// Round 2
// 296.072 us; speedup vs baseline: 7.1242x; 7.1242x over previous
//
#include <hip/hip_runtime.h>
#include <math.h>

#define D_MODEL 1024
#define NHEADS  16
#define HD      64
#define BSZ     4
#define LSEQ    1024
#define BH      64

typedef _Float16 f16;
typedef _Float16 f16x8 __attribute__((ext_vector_type(8)));
typedef _Float16 f16x4 __attribute__((ext_vector_type(4)));
typedef float    f32x4 __attribute__((ext_vector_type(4)));

typedef const __attribute__((address_space(1))) void* gp1_t;
typedef __attribute__((address_space(3))) void* lp3_t;

__device__ __forceinline__ void gload_lds16(const void* g, void* l) {
    __builtin_amdgcn_global_load_lds((gp1_t)g, (lp3_t)l, 16, 0, 0);
}

// ---------------- lambda scalars ----------------
// lam[0]=lamC=exp(sum lk*lv)  (multiplies QK term)
// lam[1]=lamS=exp(sum lq*lk)  (multiplies KV term)
// lam[2]=alpha=lamC/lamS      (pre-scales Q)
// lam[3]=gamma=0.125*lamS     (post-scales MFMA scores)
__global__ void lam_kernel(const float* __restrict__ lq, const float* __restrict__ lk,
                           const float* __restrict__ lv, float* __restrict__ lam) {
    int t = threadIdx.x; // 64 threads
    float pc = lk[t] * lv[t];
    float ps = lq[t] * lk[t];
#pragma unroll
    for (int o = 32; o > 0; o >>= 1) {
        pc += __shfl_down(pc, o, 64);
        ps += __shfl_down(ps, o, 64);
    }
    if (t == 0) {
        float lamC = expf(pc), lamS = expf(ps);
        lam[0] = lamC; lam[1] = lamS;
        lam[2] = lamC / lamS;
        lam[3] = 0.125f * lamS;
    }
}

// ---------------- fp32 -> f16 convert (weights) ----------------
__global__ void cvt_f32_f16_kernel(const float* __restrict__ src, f16* __restrict__ dst, int n8) {
    int i = blockIdx.x * blockDim.x + threadIdx.x;
    if (i < n8) {
        float4 a = *(const float4*)(src + (size_t)i * 8);
        float4 b = *(const float4*)(src + (size_t)i * 8 + 4);
        f16x8 h;
        h[0]=(f16)a.x; h[1]=(f16)a.y; h[2]=(f16)a.z; h[3]=(f16)a.w;
        h[4]=(f16)b.x; h[5]=(f16)b.y; h[6]=(f16)b.z; h[7]=(f16)b.w;
        *(f16x8*)(dst + (size_t)i * 8) = h;
    }
}

// ---------------- GEMM: Y = X @ W^T + bias (f16 MFMA) ----------------
// AMODE 0: A is fp32 (reg-cvt staging). AMODE 1: A is f16 (global_load_lds).
// OMODE 0: fp32 flat [m][n].  OMODE 1: f16 head-split * lam[2].  OMODE 2: f16 head-split.
template<int AMODE, int OMODE>
__global__ __launch_bounds__(256) void gemm16_kernel(
    const void* __restrict__ Aarg, const f16* __restrict__ B16,
    const float* __restrict__ bias, const float* __restrict__ lam,
    void* __restrict__ Yarg)
{
    __shared__ f16 At[128 * 64];   // pitch 128B, XOR-swizzled ((row&7)<<4)
    __shared__ f16 Btl[128 * 64];

    const int t = threadIdx.x;
    const int lane = t & 63, w = t >> 6;
    const int g = lane >> 4, ln = lane & 15;
    const int wr = w >> 1, wc = w & 1;
    const int n0 = blockIdx.x * 128, m0 = blockIdx.y * 128;

    f32x4 acc[4][4];
#pragma unroll
    for (int mi = 0; mi < 4; ++mi)
#pragma unroll
        for (int ni = 0; ni < 4; ++ni)
            acc[mi][ni] = (f32x4){0.f, 0.f, 0.f, 0.f};

    for (int kt = 0; kt < 16; ++kt) {
        if (AMODE == 0) {
            const float* X = (const float*)Aarg;
            int r = t >> 1, k0 = (t & 1) * 32;
            const float* src = X + (size_t)(m0 + r) * 1024 + kt * 64 + k0;
#pragma unroll
            for (int c = 0; c < 4; ++c) {
                float4 f0 = *(const float4*)(src + c * 8);
                float4 f1 = *(const float4*)(src + c * 8 + 4);
                f16x8 hv;
                hv[0]=(f16)f0.x; hv[1]=(f16)f0.y; hv[2]=(f16)f0.z; hv[3]=(f16)f0.w;
                hv[4]=(f16)f1.x; hv[5]=(f16)f1.y; hv[6]=(f16)f1.z; hv[7]=(f16)f1.w;
                int kb = (k0 + c * 8) * 2;
                *(f16x8*)((char*)At + r * 128 + (kb ^ ((r & 7) << 4))) = hv;
            }
        } else {
            const f16* A16 = (const f16*)Aarg;
#pragma unroll
            for (int i = 0; i < 4; ++i) {
                int o = t * 16 + i * 4096;
                int r = o >> 7, kb = (o & 127) ^ ((r & 7) << 4);
                gload_lds16(A16 + (size_t)(m0 + r) * 1024 + kt * 64 + (kb >> 1), (char*)At + o);
            }
        }
#pragma unroll
        for (int i = 0; i < 4; ++i) {
            int o = t * 16 + i * 4096;
            int r = o >> 7, kb = (o & 127) ^ ((r & 7) << 4);
            gload_lds16(B16 + (size_t)(n0 + r) * 1024 + kt * 64 + (kb >> 1), (char*)Btl + o);
        }
        __syncthreads();
#pragma unroll
        for (int ks = 0; ks < 2; ++ks) {
            f16x8 af[4], bf[4];
#pragma unroll
            for (int mi = 0; mi < 4; ++mi) {
                int r = wr * 64 + mi * 16 + ln;
                af[mi] = *(const f16x8*)((const char*)At + r * 128 + ((ks * 64 + g * 16) ^ ((r & 7) << 4)));
            }
#pragma unroll
            for (int ni = 0; ni < 4; ++ni) {
                int r = wc * 64 + ni * 16 + ln;
                bf[ni] = *(const f16x8*)((const char*)Btl + r * 128 + ((ks * 64 + g * 16) ^ ((r & 7) << 4)));
            }
#pragma unroll
            for (int mi = 0; mi < 4; ++mi)
#pragma unroll
                for (int ni = 0; ni < 4; ++ni)
                    acc[mi][ni] = __builtin_amdgcn_mfma_f32_16x16x32_f16(af[mi], bf[ni], acc[mi][ni], 0, 0, 0);
        }
        __syncthreads();
    }

    float alpha = 1.0f;
    if (OMODE == 1) alpha = lam[2];
#pragma unroll
    for (int mi = 0; mi < 4; ++mi) {
#pragma unroll
        for (int ni = 0; ni < 4; ++ni) {
            int n = n0 + wc * 64 + ni * 16 + ln;
            float bn = bias[n];
#pragma unroll
            for (int q = 0; q < 4; ++q) {
                int m = m0 + wr * 64 + mi * 16 + 4 * g + q;
                float v = acc[mi][ni][q] + bn;
                if (OMODE == 0) {
                    ((float*)Yarg)[(size_t)m * 1024 + n] = v;
                } else {
                    v *= alpha;
                    int b = m >> 10, l = m & 1023;
                    int h = n >> 6, d = n & 63;
                    ((f16*)Yarg)[(((size_t)(b * NHEADS + h)) * LSEQ + l) * HD + d] = (f16)v;
                }
            }
        }
    }
}

// ---------------- V transpose: Vh[bh][c][d] -> Vt[bh][d][c] ----------------
__global__ __launch_bounds__(256) void vtrans_kernel(const f16* __restrict__ Vh, f16* __restrict__ Vt) {
    __shared__ f16 tile[64 * 72];   // pitch 144B
    int t = threadIdx.x;
    int cb = blockIdx.x;            // 16 column blocks
    int bh = blockIdx.y;
    size_t base = (size_t)bh * LSEQ * HD;
    {
        int c = t >> 2, d0 = (t & 3) * 16;
        f16x8 v0 = *(const f16x8*)(Vh + base + (size_t)(cb * 64 + c) * HD + d0);
        f16x8 v1 = *(const f16x8*)(Vh + base + (size_t)(cb * 64 + c) * HD + d0 + 8);
        *(f16x8*)((char*)tile + c * 144 + d0 * 2) = v0;
        *(f16x8*)((char*)tile + c * 144 + d0 * 2 + 16) = v1;
    }
    __syncthreads();
    {
        int d = t >> 2, c0 = (t & 3) * 16;
        f16 buf[16];
#pragma unroll
        for (int j = 0; j < 16; ++j)
            buf[j] = *(const f16*)((const char*)tile + (c0 + j) * 144 + d * 2);
        f16x8 o0, o1;
#pragma unroll
        for (int j = 0; j < 8; ++j) { o0[j] = buf[j]; o1[j] = buf[j + 8]; }
        size_t ob = (size_t)bh * HD * LSEQ + (size_t)d * LSEQ + cb * 64 + c0;
        *(f16x8*)(Vt + ob) = o0;
        *(f16x8*)(Vt + ob + 8) = o1;
    }
}

// ---------------- fused attention: scores -> softmax (weights out) -> PV ----------------
// Per block: one (b,h), 64 query rows, 4 waves (wave w owns rows 16w..16w+15).
// Combined K=128: A-side rows = [alpha*Q | K] (Qt), B-side rows = [K | V] (Bt).
// Scores computed TRANSPOSED: S^T = mfma(A=KV-frags, B=Q-frags) so each lane's
// accum quad is contiguous in the key dim (float4 attnW stores, easy f16 pack).
__global__ __launch_bounds__(256) void attn_kernel(
    const f16* __restrict__ Qs, const f16* __restrict__ Kh, const f16* __restrict__ Vh,
    const f16* __restrict__ Vt, const float* __restrict__ lam,
    float* __restrict__ attnW, f16* __restrict__ AO)
{
    __shared__ f16 Qt[64 * 128];    // [r][k0..127] pitch 256B, swizzled ((r&7)<<4)
    __shared__ f16 Bt[64 * 128];    // [c][k0..127] pitch 256B, swizzled
    __shared__ f16 Vts[64 * 64];    // [d][c] pitch 128B, swizzled
    __shared__ f16 Ws[64 * 72];     // [r][c] pitch 144B (natural 2-way banks)
    __shared__ float linv[64];

    const int t = threadIdx.x;
    const int lane = t & 63;
    const int w = t >> 6;
    const int g = lane >> 4;
    const int ln = lane & 15;
    const int rb = blockIdx.x;      // 0..15
    const int bh = blockIdx.y;      // 0..63
    const size_t hbase = (size_t)bh * LSEQ * HD;
    const float gamma = lam[3];

    // stage Qt rows r: [alpha*Q | K] of global row rb*64+r
    {
        const int r0 = rb * 64;
#pragma unroll
        for (int i = 0; i < 4; ++i) {
            int o = t * 16 + i * 4096;
            int r = o >> 8, kb = (o & 255) ^ ((r & 7) << 4);
            const f16* src = (kb < 128) ? (Qs + hbase + (size_t)(r0 + r) * HD + (kb >> 1))
                                        : (Kh + hbase + (size_t)(r0 + r) * HD + ((kb - 128) >> 1));
            gload_lds16(src, (char*)Qt + o);
        }
    }
    __syncthreads();

    // preload Q-side B-frags into registers (reused across all 32 tile iterations)
    f16x8 qf[4];
    {
        int r = w * 16 + ln;
#pragma unroll
        for (int ks = 0; ks < 4; ++ks)
            qf[ks] = *(const f16x8*)((const char*)Qt + r * 256 + ((ks * 64 + g * 16) ^ ((r & 7) << 4)));
    }

    // ---------- pass 1: row sums of exp(scores) ----------
    float lsum = 0.f;
    for (int tt = 0; tt < 16; ++tt) {
        {
            const int c0 = tt * 64;
#pragma unroll
            for (int i = 0; i < 4; ++i) {
                int o = t * 16 + i * 4096;
                int r = o >> 8, kb = (o & 255) ^ ((r & 7) << 4);
                const f16* src = (kb < 128) ? (Kh + hbase + (size_t)(c0 + r) * HD + (kb >> 1))
                                            : (Vh + hbase + (size_t)(c0 + r) * HD + ((kb - 128) >> 1));
                gload_lds16(src, (char*)Bt + o);
            }
        }
        __syncthreads();
#pragma unroll
        for (int ci = 0; ci < 4; ++ci) {
            f32x4 acc = (f32x4){0.f, 0.f, 0.f, 0.f};
#pragma unroll
            for (int ks = 0; ks < 4; ++ks) {
                int c = ci * 16 + ln;
                f16x8 af = *(const f16x8*)((const char*)Bt + c * 256 + ((ks * 64 + g * 16) ^ ((c & 7) << 4)));
                acc = __builtin_amdgcn_mfma_f32_16x16x32_f16(af, qf[ks], acc, 0, 0, 0);
            }
#pragma unroll
            for (int q = 0; q < 4; ++q) lsum += __expf(acc[q] * gamma);
        }
        __syncthreads();
    }
    lsum += __shfl_xor(lsum, 16, 64);
    lsum += __shfl_xor(lsum, 32, 64);
    if (g == 0) linv[w * 16 + ln] = 1.0f / lsum;
    __syncthreads();

    // ---------- pass 2: weights write + PV ----------
    f32x4 oacc[4];
#pragma unroll
    for (int dj = 0; dj < 4; ++dj) oacc[dj] = (f32x4){0.f, 0.f, 0.f, 0.f};

    for (int tt = 0; tt < 16; ++tt) {
        {
            const int c0 = tt * 64;
#pragma unroll
            for (int i = 0; i < 4; ++i) {
                int o = t * 16 + i * 4096;
                int r = o >> 8, kb = (o & 255) ^ ((r & 7) << 4);
                const f16* src = (kb < 128) ? (Kh + hbase + (size_t)(c0 + r) * HD + (kb >> 1))
                                            : (Vh + hbase + (size_t)(c0 + r) * HD + ((kb - 128) >> 1));
                gload_lds16(src, (char*)Bt + o);
            }
#pragma unroll
            for (int i = 0; i < 2; ++i) {
                int o = t * 16 + i * 4096;
                int r = o >> 7, kb = (o & 127) ^ ((r & 7) << 4);
                const f16* src = Vt + (size_t)bh * HD * LSEQ + (size_t)r * LSEQ + tt * 64 + (kb >> 1);
                gload_lds16(src, (char*)Vts + o);
            }
        }
        __syncthreads();

        // scores (recompute) -> normalized weights -> global + LDS(f16)
        {
            int r = w * 16 + ln;
            float il = linv[r];
#pragma unroll
            for (int ci = 0; ci < 4; ++ci) {
                f32x4 acc = (f32x4){0.f, 0.f, 0.f, 0.f};
#pragma unroll
                for (int ks = 0; ks < 4; ++ks) {
                    int c = ci * 16 + ln;
                    f16x8 af = *(const f16x8*)((const char*)Bt + c * 256 + ((ks * 64 + g * 16) ^ ((c & 7) << 4)));
                    acc = __builtin_amdgcn_mfma_f32_16x16x32_f16(af, qf[ks], acc, 0, 0, 0);
                }
                float4 wv;
                wv.x = __expf(acc[0] * gamma) * il;
                wv.y = __expf(acc[1] * gamma) * il;
                wv.z = __expf(acc[2] * gamma) * il;
                wv.w = __expf(acc[3] * gamma) * il;
                size_t gi = (((size_t)bh * LSEQ) + rb * 64 + r) * LSEQ + tt * 64 + ci * 16 + 4 * g;
                *(float4*)(attnW + gi) = wv;
                f16x4 wh;
                wh[0] = (f16)wv.x; wh[1] = (f16)wv.y; wh[2] = (f16)wv.z; wh[3] = (f16)wv.w;
                *(f16x4*)((char*)Ws + r * 144 + ci * 32 + g * 8) = wh;
            }
        }
        // PV: O[r][d] += W[r][c] * V[c][d]   (same-wave Ws producer/consumer; DS in-order)
#pragma unroll
        for (int ks = 0; ks < 2; ++ks) {
            int r = w * 16 + ln;
            f16x8 pa = *(const f16x8*)((const char*)Ws + r * 144 + ks * 64 + g * 16);
#pragma unroll
            for (int dj = 0; dj < 4; ++dj) {
                int d = dj * 16 + ln;
                f16x8 vb = *(const f16x8*)((const char*)Vts + d * 128 + ((ks * 64 + g * 16) ^ ((d & 7) << 4)));
                oacc[dj] = __builtin_amdgcn_mfma_f32_16x16x32_f16(pa, vb, oacc[dj], 0, 0, 0);
            }
        }
        __syncthreads();
    }

    // write AO (f16, merged-head [b][l][h*64+d]) — C-layout: row=4g+q, col=ln
    {
        const int b = bh >> 4, h = bh & 15;
#pragma unroll
        for (int dj = 0; dj < 4; ++dj)
#pragma unroll
            for (int q = 0; q < 4; ++q) {
                int l = rb * 64 + w * 16 + 4 * g + q;
                int col = h * 64 + dj * 16 + ln;
                AO[((size_t)b * LSEQ + l) * D_MODEL + col] = (f16)oacc[dj][q];
            }
    }
}

extern "C" void kernel_launch(void* const* d_in, const int* in_sizes, int n_in,
                              void* d_out, int out_size, void* d_ws, size_t ws_size,
                              hipStream_t stream) {
    const float* q  = (const float*)d_in[0];
    const float* k  = (const float*)d_in[1];
    const float* v  = (const float*)d_in[2];
    const float* Wq = (const float*)d_in[3];
    const float* bq = (const float*)d_in[4];
    const float* Wk = (const float*)d_in[5];
    const float* bk = (const float*)d_in[6];
    const float* Wv = (const float*)d_in[7];
    const float* bv = (const float*)d_in[8];
    const float* Wo = (const float*)d_in[9];
    const float* bo = (const float*)d_in[10];
    const float* lq = (const float*)d_in[11];
    const float* lk = (const float*)d_in[12];
    const float* lv = (const float*)d_in[13];

    float* out   = (float*)d_out;                          // [4,1024,1024] fp32
    float* attnW = out + (size_t)BSZ * LSEQ * D_MODEL;     // [4,16,1024,1024] fp32

    f16* ws16 = (f16*)d_ws;
    const size_t HSZ = (size_t)BH * LSEQ * HD;             // 4194304
    f16* Qs   = ws16;                  // alpha-scaled Q, head-split
    f16* Kh   = ws16 + HSZ;
    f16* Vh   = ws16 + 2 * HSZ;
    f16* Vt   = ws16 + 3 * HSZ;        // [bh][d][l]
    f16* AO   = ws16 + 4 * HSZ;        // [b][l][D] f16
    f16* W16q = ws16 + 5 * HSZ;
    f16* W16k = W16q + 1048576;
    f16* W16v = W16k + 1048576;
    f16* W16o = W16v + 1048576;
    float* lam = (float*)(W16o + 1048576);

    lam_kernel<<<1, 64, 0, stream>>>(lq, lk, lv, lam);

    cvt_f32_f16_kernel<<<512, 256, 0, stream>>>(Wq, W16q, 131072);
    cvt_f32_f16_kernel<<<512, 256, 0, stream>>>(Wk, W16k, 131072);
    cvt_f32_f16_kernel<<<512, 256, 0, stream>>>(Wv, W16v, 131072);
    cvt_f32_f16_kernel<<<512, 256, 0, stream>>>(Wo, W16o, 131072);

    dim3 ggrid(8, 32);
    gemm16_kernel<0, 1><<<ggrid, 256, 0, stream>>>((const void*)q, W16q, bq, lam, (void*)Qs);
    gemm16_kernel<0, 2><<<ggrid, 256, 0, stream>>>((const void*)k, W16k, bk, lam, (void*)Kh);
    gemm16_kernel<0, 2><<<ggrid, 256, 0, stream>>>((const void*)v, W16v, bv, lam, (void*)Vh);

    vtrans_kernel<<<dim3(16, 64), 256, 0, stream>>>(Vh, Vt);

    attn_kernel<<<dim3(16, 64), 256, 0, stream>>>(Qs, Kh, Vh, Vt, lam, attnW, AO);

    gemm16_kernel<1, 0><<<ggrid, 256, 0, stream>>>((const void*)AO, W16o, bo, lam, (void*)out);
}

// Round 3
// 247.678 us; speedup vs baseline: 8.5162x; 1.1954x over previous
//
#include <hip/hip_runtime.h>
#include <math.h>

#define D_MODEL 1024
#define NHEADS  16
#define HD      64
#define BSZ     4
#define LSEQ    1024
#define BH      64

typedef _Float16 f16;
typedef _Float16 f16x8 __attribute__((ext_vector_type(8)));
typedef _Float16 f16x4 __attribute__((ext_vector_type(4)));
typedef float    f32x4 __attribute__((ext_vector_type(4)));

typedef const __attribute__((address_space(1))) void* gp1_t;
typedef __attribute__((address_space(3))) void* lp3_t;

__device__ __forceinline__ void gload_lds16(const void* g, void* l) {
    __builtin_amdgcn_global_load_lds((gp1_t)g, (lp3_t)l, 16, 0, 0);
}

// ---------------- lambda scalars ----------------
__global__ void lam_kernel(const float* __restrict__ lq, const float* __restrict__ lk,
                           const float* __restrict__ lv, float* __restrict__ lam) {
    int t = threadIdx.x; // 64 threads
    float pc = lk[t] * lv[t];
    float ps = lq[t] * lk[t];
#pragma unroll
    for (int o = 32; o > 0; o >>= 1) {
        pc += __shfl_down(pc, o, 64);
        ps += __shfl_down(ps, o, 64);
    }
    if (t == 0) {
        float lamC = expf(pc), lamS = expf(ps);
        lam[0] = lamC; lam[1] = lamS;
        lam[2] = lamC / lamS;        // alpha: pre-scales Q
        lam[3] = 0.125f * lamS;      // gamma: post-scales MFMA scores
    }
}

// ---------------- fp32 -> f16 convert: all four weights in one launch ----------------
__global__ __launch_bounds__(256) void cvt4_kernel(
    const float* __restrict__ s0, const float* __restrict__ s1,
    const float* __restrict__ s2, const float* __restrict__ s3,
    f16* __restrict__ d0, f16* __restrict__ d1, f16* __restrict__ d2, f16* __restrict__ d3) {
    int which = blockIdx.y;
    const float* src = which == 0 ? s0 : which == 1 ? s1 : which == 2 ? s2 : s3;
    f16* dst = which == 0 ? d0 : which == 1 ? d1 : which == 2 ? d2 : d3;
    int i = blockIdx.x * blockDim.x + threadIdx.x;   // 131072 per weight
    float4 a = *(const float4*)(src + (size_t)i * 8);
    float4 b = *(const float4*)(src + (size_t)i * 8 + 4);
    f16x8 h;
    h[0]=(f16)a.x; h[1]=(f16)a.y; h[2]=(f16)a.z; h[3]=(f16)a.w;
    h[4]=(f16)b.x; h[5]=(f16)b.y; h[6]=(f16)b.z; h[7]=(f16)b.w;
    *(f16x8*)(dst + (size_t)i * 8) = h;
}

// ---------------- merged QKV projection: Y = X @ W^T + bias (f16 MFMA, dbuf) ----------------
// z=0: Qs (head-split f16, *alpha)   z=1: Kh   z=2: Vh + Vt (transposed copy)
__global__ __launch_bounds__(256, 2) void gemm_qkv_kernel(
    const float* __restrict__ q, const float* __restrict__ k, const float* __restrict__ v,
    const f16* __restrict__ Wq, const f16* __restrict__ Wk, const f16* __restrict__ Wv,
    const float* __restrict__ bq, const float* __restrict__ bk, const float* __restrict__ bv,
    const float* __restrict__ lam,
    f16* __restrict__ Qs, f16* __restrict__ Kh, f16* __restrict__ Vh, f16* __restrict__ Vt)
{
    __shared__ f16 At[2][128 * 64];   // pitch 128B, XOR-swizzled ((row&7)<<4)
    __shared__ f16 Bt[2][128 * 64];

    const int z = blockIdx.z;
    const float* X    = (z == 0) ? q  : (z == 1) ? k  : v;
    const f16*   W    = (z == 0) ? Wq : (z == 1) ? Wk : Wv;
    const float* bias = (z == 0) ? bq : (z == 1) ? bk : bv;

    const int t = threadIdx.x;
    const int lane = t & 63, w = t >> 6;
    const int g = lane >> 4, ln = lane & 15;
    const int wr = w >> 1, wc = w & 1;
    const int n0 = blockIdx.x * 128, m0 = blockIdx.y * 128;
    const int ar = t >> 1, ak = (t & 1) * 32;   // fp32 A staging: row, col-base

    f32x4 acc[4][4];
#pragma unroll
    for (int mi = 0; mi < 4; ++mi)
#pragma unroll
        for (int ni = 0; ni < 4; ++ni)
            acc[mi][ni] = (f32x4){0.f, 0.f, 0.f, 0.f};

    // prologue: stage tile 0
    {
        const float* src = X + (size_t)(m0 + ar) * 1024 + ak;
#pragma unroll
        for (int c = 0; c < 4; ++c) {
            float4 f0 = ((const float4*)src)[c * 2];
            float4 f1 = ((const float4*)src)[c * 2 + 1];
            f16x8 hv;
            hv[0]=(f16)f0.x; hv[1]=(f16)f0.y; hv[2]=(f16)f0.z; hv[3]=(f16)f0.w;
            hv[4]=(f16)f1.x; hv[5]=(f16)f1.y; hv[6]=(f16)f1.z; hv[7]=(f16)f1.w;
            int kb = (ak + c * 8) * 2;
            *(f16x8*)((char*)At[0] + ar * 128 + (kb ^ ((ar & 7) << 4))) = hv;
        }
#pragma unroll
        for (int i = 0; i < 4; ++i) {
            int o = t * 16 + i * 4096;
            int r = o >> 7, kb = (o & 127) ^ ((r & 7) << 4);
            gload_lds16(W + (size_t)(n0 + r) * 1024 + (kb >> 1), (char*)Bt[0] + o);
        }
    }
    __syncthreads();

    int cur = 0;
    for (int kt = 0; kt < 16; ++kt) {
        float4 pre[8];
        if (kt < 15) {
            // T14 issue-early: global A loads to regs + B gload_lds into next buffer
            const float* src = X + (size_t)(m0 + ar) * 1024 + (kt + 1) * 64 + ak;
#pragma unroll
            for (int c = 0; c < 8; ++c) pre[c] = ((const float4*)src)[c];
#pragma unroll
            for (int i = 0; i < 4; ++i) {
                int o = t * 16 + i * 4096;
                int r = o >> 7, kb = (o & 127) ^ ((r & 7) << 4);
                gload_lds16(W + (size_t)(n0 + r) * 1024 + (kt + 1) * 64 + (kb >> 1),
                            (char*)Bt[cur ^ 1] + o);
            }
        }
        // compute current tile
#pragma unroll
        for (int ks = 0; ks < 2; ++ks) {
            f16x8 af[4], bf[4];
#pragma unroll
            for (int mi = 0; mi < 4; ++mi) {
                int r = wr * 64 + mi * 16 + ln;
                af[mi] = *(const f16x8*)((const char*)At[cur] + r * 128 + ((ks * 64 + g * 16) ^ ((r & 7) << 4)));
            }
#pragma unroll
            for (int ni = 0; ni < 4; ++ni) {
                int r = wc * 64 + ni * 16 + ln;
                bf[ni] = *(const f16x8*)((const char*)Bt[cur] + r * 128 + ((ks * 64 + g * 16) ^ ((r & 7) << 4)));
            }
#pragma unroll
            for (int mi = 0; mi < 4; ++mi)
#pragma unroll
                for (int ni = 0; ni < 4; ++ni)
                    acc[mi][ni] = __builtin_amdgcn_mfma_f32_16x16x32_f16(af[mi], bf[ni], acc[mi][ni], 0, 0, 0);
        }
        if (kt < 15) {
            // write-late: cvt + ds_write A next buffer
#pragma unroll
            for (int c = 0; c < 4; ++c) {
                float4 f0 = pre[c * 2], f1 = pre[c * 2 + 1];
                f16x8 hv;
                hv[0]=(f16)f0.x; hv[1]=(f16)f0.y; hv[2]=(f16)f0.z; hv[3]=(f16)f0.w;
                hv[4]=(f16)f1.x; hv[5]=(f16)f1.y; hv[6]=(f16)f1.z; hv[7]=(f16)f1.w;
                int kb = (ak + c * 8) * 2;
                *(f16x8*)((char*)At[cur ^ 1] + ar * 128 + (kb ^ ((ar & 7) << 4))) = hv;
            }
        }
        __syncthreads();
        cur ^= 1;
    }

    const float alpha = (z == 0) ? lam[2] : 1.0f;
    f16* Y = (z == 0) ? Qs : (z == 1) ? Kh : Vh;
#pragma unroll
    for (int mi = 0; mi < 4; ++mi) {
#pragma unroll
        for (int ni = 0; ni < 4; ++ni) {
            int n = n0 + wc * 64 + ni * 16 + ln;
            int h = n >> 6, d = n & 63;
            float bn = bias[n];
            int mrow0 = m0 + wr * 64 + mi * 16 + 4 * g;
            int b = mrow0 >> 10, l0 = mrow0 & 1023;
            f16x4 tv;
#pragma unroll
            for (int qq = 0; qq < 4; ++qq) {
                float val = (acc[mi][ni][qq] + bn) * alpha;
                f16 hq = (f16)val;
                tv[qq] = hq;
                Y[(((size_t)(b * NHEADS + h)) * LSEQ + l0 + qq) * HD + d] = hq;
            }
            if (z == 2)
                *(f16x4*)(Vt + ((size_t)(b * NHEADS + h) * HD + d) * LSEQ + l0) = tv;
        }
    }
}

// ---------------- AO GEMM: out = AO @ Wo^T + bo (f16 A, fp32 out, dbuf) ----------------
__global__ __launch_bounds__(256, 2) void gemm_ao_kernel(
    const f16* __restrict__ A16, const f16* __restrict__ W16,
    const float* __restrict__ bias, float* __restrict__ out)
{
    __shared__ f16 At[2][128 * 64];
    __shared__ f16 Bt[2][128 * 64];

    const int t = threadIdx.x;
    const int lane = t & 63, w = t >> 6;
    const int g = lane >> 4, ln = lane & 15;
    const int wr = w >> 1, wc = w & 1;
    const int n0 = blockIdx.x * 128, m0 = blockIdx.y * 128;

    f32x4 acc[4][4];
#pragma unroll
    for (int mi = 0; mi < 4; ++mi)
#pragma unroll
        for (int ni = 0; ni < 4; ++ni)
            acc[mi][ni] = (f32x4){0.f, 0.f, 0.f, 0.f};

#pragma unroll
    for (int i = 0; i < 4; ++i) {
        int o = t * 16 + i * 4096;
        int r = o >> 7, kb = (o & 127) ^ ((r & 7) << 4);
        gload_lds16(A16 + (size_t)(m0 + r) * 1024 + (kb >> 1), (char*)At[0] + o);
        gload_lds16(W16 + (size_t)(n0 + r) * 1024 + (kb >> 1), (char*)Bt[0] + o);
    }
    __syncthreads();

    int cur = 0;
    for (int kt = 0; kt < 16; ++kt) {
        if (kt < 15) {
#pragma unroll
            for (int i = 0; i < 4; ++i) {
                int o = t * 16 + i * 4096;
                int r = o >> 7, kb = (o & 127) ^ ((r & 7) << 4);
                gload_lds16(A16 + (size_t)(m0 + r) * 1024 + (kt + 1) * 64 + (kb >> 1), (char*)At[cur ^ 1] + o);
                gload_lds16(W16 + (size_t)(n0 + r) * 1024 + (kt + 1) * 64 + (kb >> 1), (char*)Bt[cur ^ 1] + o);
            }
        }
#pragma unroll
        for (int ks = 0; ks < 2; ++ks) {
            f16x8 af[4], bf[4];
#pragma unroll
            for (int mi = 0; mi < 4; ++mi) {
                int r = wr * 64 + mi * 16 + ln;
                af[mi] = *(const f16x8*)((const char*)At[cur] + r * 128 + ((ks * 64 + g * 16) ^ ((r & 7) << 4)));
            }
#pragma unroll
            for (int ni = 0; ni < 4; ++ni) {
                int r = wc * 64 + ni * 16 + ln;
                bf[ni] = *(const f16x8*)((const char*)Bt[cur] + r * 128 + ((ks * 64 + g * 16) ^ ((r & 7) << 4)));
            }
#pragma unroll
            for (int mi = 0; mi < 4; ++mi)
#pragma unroll
                for (int ni = 0; ni < 4; ++ni)
                    acc[mi][ni] = __builtin_amdgcn_mfma_f32_16x16x32_f16(af[mi], bf[ni], acc[mi][ni], 0, 0, 0);
        }
        __syncthreads();
        cur ^= 1;
    }

#pragma unroll
    for (int mi = 0; mi < 4; ++mi)
#pragma unroll
        for (int ni = 0; ni < 4; ++ni) {
            int n = n0 + wc * 64 + ni * 16 + ln;
            float bn = bias[n];
#pragma unroll
            for (int qq = 0; qq < 4; ++qq) {
                int m = m0 + wr * 64 + mi * 16 + 4 * g + qq;
                out[(size_t)m * 1024 + n] = acc[mi][ni][qq] + bn;
            }
        }
}

// ---------------- fused attention: 128 q-rows/block, 8 waves, dbuf, 2-pass ----------------
__global__ __launch_bounds__(512, 4) void attn_kernel(
    const f16* __restrict__ Qs, const f16* __restrict__ Kh, const f16* __restrict__ Vh,
    const f16* __restrict__ Vt, const float* __restrict__ lam,
    float* __restrict__ attnW, f16* __restrict__ AO)
{
    // 80 KB exactly: Qt(32K, aliased by Ws in pass 2) | Bt dbuf(2x16K) | Vts dbuf(2x8K)
    __shared__ char smem[81920];
    char* QtWs = smem;            // Qt: 128 rows x 256B, swizzle ((r&7)<<4); Ws: 128 rows x 144B
    char* BtB  = smem + 32768;    // [c][K|V] 64 rows x 256B, swizzled; two buffers
    char* VtsB = smem + 65536;    // [d][c] 64 rows x 128B, swizzled; two buffers

    const int t = threadIdx.x;           // 0..511
    const int lane = t & 63, w = t >> 6; // 8 waves, wave w owns q-rows w*16..w*16+15
    const int g = lane >> 4, ln = lane & 15;

    const int bid = blockIdx.x;                       // 0..511
    const int wg = (bid & 7) * 64 + (bid >> 3);       // XCD-contiguous swizzle
    const int bh = wg >> 3, rb = wg & 7;
    const size_t hbase = (size_t)bh * LSEQ * HD;
    const float gamma = lam[3];

    // stage Qt rows: [alpha*Q | K] of global rows rb*128 ..
    {
        const int r0 = rb * 128;
#pragma unroll
        for (int i = 0; i < 4; ++i) {
            int o = t * 16 + i * 8192;
            int r = o >> 8, kb = (o & 255) ^ ((r & 7) << 4);
            const f16* src = (kb < 128) ? (Qs + hbase + (size_t)(r0 + r) * HD + (kb >> 1))
                                        : (Kh + hbase + (size_t)(r0 + r) * HD + ((kb - 128) >> 1));
            gload_lds16(src, QtWs + o);
        }
    }
    // stage Bt[0] = tile 0 [K|V]
#pragma unroll
    for (int i = 0; i < 2; ++i) {
        int o = t * 16 + i * 8192;
        int r = o >> 8, kb = (o & 255) ^ ((r & 7) << 4);
        const f16* src = (kb < 128) ? (Kh + hbase + (size_t)r * HD + (kb >> 1))
                                    : (Vh + hbase + (size_t)r * HD + ((kb - 128) >> 1));
        gload_lds16(src, BtB + o);
    }
    __syncthreads();

    // preload Q-side B-frags (frees Qt region for Ws)
    f16x8 qf[4];
    {
        int r = w * 16 + ln;
#pragma unroll
        for (int ks = 0; ks < 4; ++ks)
            qf[ks] = *(const f16x8*)(QtWs + r * 256 + ((ks * 64 + g * 16) ^ ((r & 7) << 4)));
    }

    // ---------- pass 1: row sums of exp ----------
    float lsum = 0.f;
    int cur = 0;
    for (int tt = 0; tt < 16; ++tt) {
        {   // prefetch next tile (tt==15 wraps to tile 0 for pass 2, plus its Vts)
            const int c0 = ((tt + 1) & 15) * 64;
#pragma unroll
            for (int i = 0; i < 2; ++i) {
                int o = t * 16 + i * 8192;
                int r = o >> 8, kb = (o & 255) ^ ((r & 7) << 4);
                const f16* src = (kb < 128) ? (Kh + hbase + (size_t)(c0 + r) * HD + (kb >> 1))
                                            : (Vh + hbase + (size_t)(c0 + r) * HD + ((kb - 128) >> 1));
                gload_lds16(src, BtB + (cur ^ 1) * 16384 + o);
            }
            if (tt == 15) {
                int o = t * 16;
                int d = o >> 7, kb = (o & 127) ^ ((d & 7) << 4);
                gload_lds16(Vt + (size_t)bh * HD * LSEQ + (size_t)d * LSEQ + (kb >> 1),
                            VtsB + (cur ^ 1) * 8192 + o);
            }
        }
#pragma unroll
        for (int ci = 0; ci < 4; ++ci) {
            f32x4 acc = (f32x4){0.f, 0.f, 0.f, 0.f};
#pragma unroll
            for (int ks = 0; ks < 4; ++ks) {
                int c = ci * 16 + ln;
                f16x8 af = *(const f16x8*)(BtB + cur * 16384 + c * 256 + ((ks * 64 + g * 16) ^ ((c & 7) << 4)));
                acc = __builtin_amdgcn_mfma_f32_16x16x32_f16(af, qf[ks], acc, 0, 0, 0);
            }
#pragma unroll
            for (int qq = 0; qq < 4; ++qq) lsum += __expf(acc[qq] * gamma);
        }
        __syncthreads();
        cur ^= 1;
    }
    lsum += __shfl_xor(lsum, 16, 64);
    lsum += __shfl_xor(lsum, 32, 64);
    const float il = 1.0f / lsum;    // every lane holds its row's (w*16+ln) inverse sum

    // ---------- pass 2: weights write + PV ----------
    f32x4 oacc[4];
#pragma unroll
    for (int dj = 0; dj < 4; ++dj) oacc[dj] = (f32x4){0.f, 0.f, 0.f, 0.f};

    for (int tt = 0; tt < 16; ++tt) {
        if (tt < 15) {
            const int c0 = (tt + 1) * 64;
#pragma unroll
            for (int i = 0; i < 2; ++i) {
                int o = t * 16 + i * 8192;
                int r = o >> 8, kb = (o & 255) ^ ((r & 7) << 4);
                const f16* src = (kb < 128) ? (Kh + hbase + (size_t)(c0 + r) * HD + (kb >> 1))
                                            : (Vh + hbase + (size_t)(c0 + r) * HD + ((kb - 128) >> 1));
                gload_lds16(src, BtB + (cur ^ 1) * 16384 + o);
            }
            {
                int o = t * 16;
                int d = o >> 7, kb = (o & 127) ^ ((d & 7) << 4);
                gload_lds16(Vt + (size_t)bh * HD * LSEQ + (size_t)d * LSEQ + c0 + (kb >> 1),
                            VtsB + (cur ^ 1) * 8192 + o);
            }
        }
        // scores recompute -> normalized weights -> global(nt) + LDS(f16)
        {
            const int r = w * 16 + ln;
#pragma unroll
            for (int ci = 0; ci < 4; ++ci) {
                f32x4 acc = (f32x4){0.f, 0.f, 0.f, 0.f};
#pragma unroll
                for (int ks = 0; ks < 4; ++ks) {
                    int c = ci * 16 + ln;
                    f16x8 af = *(const f16x8*)(BtB + cur * 16384 + c * 256 + ((ks * 64 + g * 16) ^ ((c & 7) << 4)));
                    acc = __builtin_amdgcn_mfma_f32_16x16x32_f16(af, qf[ks], acc, 0, 0, 0);
                }
                f32x4 wv;
                wv[0] = __expf(acc[0] * gamma) * il;
                wv[1] = __expf(acc[1] * gamma) * il;
                wv[2] = __expf(acc[2] * gamma) * il;
                wv[3] = __expf(acc[3] * gamma) * il;
                size_t gi = ((size_t)bh * LSEQ + rb * 128 + r) * LSEQ + tt * 64 + ci * 16 + 4 * g;
                __builtin_nontemporal_store(wv, (f32x4*)(attnW + gi));
                f16x4 wh;
                wh[0] = (f16)wv[0]; wh[1] = (f16)wv[1]; wh[2] = (f16)wv[2]; wh[3] = (f16)wv[3];
                *(f16x4*)(QtWs + r * 144 + ci * 32 + g * 8) = wh;
            }
        }
        // PV: same-wave Ws producer/consumer (DS in-order per wave)
#pragma unroll
        for (int ks = 0; ks < 2; ++ks) {
            int r = w * 16 + ln;
            f16x8 pa = *(const f16x8*)(QtWs + r * 144 + ks * 64 + g * 16);
#pragma unroll
            for (int dj = 0; dj < 4; ++dj) {
                int d = dj * 16 + ln;
                f16x8 vb = *(const f16x8*)(VtsB + cur * 8192 + d * 128 + ((ks * 64 + g * 16) ^ ((d & 7) << 4)));
                oacc[dj] = __builtin_amdgcn_mfma_f32_16x16x32_f16(pa, vb, oacc[dj], 0, 0, 0);
            }
        }
        __syncthreads();
        cur ^= 1;
    }

    // AO write (f16, merged-head)
    {
        const int b = bh >> 4, h = bh & 15;
#pragma unroll
        for (int dj = 0; dj < 4; ++dj)
#pragma unroll
            for (int qq = 0; qq < 4; ++qq) {
                int l = rb * 128 + w * 16 + 4 * g + qq;
                AO[((size_t)b * LSEQ + l) * D_MODEL + h * 64 + dj * 16 + ln] = (f16)oacc[dj][qq];
            }
    }
}

extern "C" void kernel_launch(void* const* d_in, const int* in_sizes, int n_in,
                              void* d_out, int out_size, void* d_ws, size_t ws_size,
                              hipStream_t stream) {
    const float* q  = (const float*)d_in[0];
    const float* k  = (const float*)d_in[1];
    const float* v  = (const float*)d_in[2];
    const float* Wq = (const float*)d_in[3];
    const float* bq = (const float*)d_in[4];
    const float* Wk = (const float*)d_in[5];
    const float* bk = (const float*)d_in[6];
    const float* Wv = (const float*)d_in[7];
    const float* bv = (const float*)d_in[8];
    const float* Wo = (const float*)d_in[9];
    const float* bo = (const float*)d_in[10];
    const float* lq = (const float*)d_in[11];
    const float* lk = (const float*)d_in[12];
    const float* lv = (const float*)d_in[13];

    float* out   = (float*)d_out;                          // [4,1024,1024] fp32
    float* attnW = out + (size_t)BSZ * LSEQ * D_MODEL;     // [4,16,1024,1024] fp32

    f16* ws16 = (f16*)d_ws;
    const size_t HSZ = (size_t)BH * LSEQ * HD;             // 4194304
    f16* Qs   = ws16;
    f16* Kh   = ws16 + HSZ;
    f16* Vh   = ws16 + 2 * HSZ;
    f16* Vt   = ws16 + 3 * HSZ;        // [bh][d][l]
    f16* AO   = ws16 + 4 * HSZ;        // [b][l][D]
    f16* W16q = ws16 + 5 * HSZ;
    f16* W16k = W16q + 1048576;
    f16* W16v = W16k + 1048576;
    f16* W16o = W16v + 1048576;
    float* lam = (float*)(W16o + 1048576);

    lam_kernel<<<1, 64, 0, stream>>>(lq, lk, lv, lam);

    cvt4_kernel<<<dim3(512, 4), 256, 0, stream>>>(Wq, Wk, Wv, Wo, W16q, W16k, W16v, W16o);

    gemm_qkv_kernel<<<dim3(8, 32, 3), 256, 0, stream>>>(
        q, k, v, W16q, W16k, W16v, bq, bk, bv, lam, Qs, Kh, Vh, Vt);

    attn_kernel<<<512, 512, 0, stream>>>(Qs, Kh, Vh, Vt, lam, attnW, AO);

    gemm_ao_kernel<<<dim3(8, 32), 256, 0, stream>>>(AO, W16o, bo, out);
}